// Round 1
// baseline (389.113 us; speedup 1.0000x reference)
//
#include <hip/hip_runtime.h>

typedef __attribute__((ext_vector_type(8))) short short8;
typedef __attribute__((ext_vector_type(4))) float float4v;

#define HB 256   // degree-histogram blocks inside fused_pre

__device__ __forceinline__ unsigned short f2bf(float f) {
    union { float f; unsigned u; } v; v.f = f;
    unsigned r = v.u + 0x7fffu + ((v.u >> 16) & 1u);   // round-to-nearest-even
    return (unsigned short)(r >> 16);
}
__device__ __forceinline__ float bf2f(unsigned short u) {
    union { unsigned u; float f; } v; v.u = ((unsigned)u) << 16; return v.f;
}

// ---------------- K1: fused [deg-histogram | LN+ReLU | W-prep] ----------
// b < HB:               grid-stride per-node degree histogram (global atomics)
// HB <= b < HB+LNB:     LayerNorm+ReLU -> packed bf16 h (wave per row)
// else (16 blocks):     pack W fragments (MFMA B layout)
__global__ __launch_bounds__(256) void fused_pre_kernel(
    const float* __restrict__ x, const float* __restrict__ gamma,
    const float* __restrict__ beta, unsigned* __restrict__ hbuf,
    const int* __restrict__ idx, int* __restrict__ deg,
    const float* __restrict__ Wl, const float* __restrict__ Wr,
    unsigned short* __restrict__ wsb, int N, int E, int LNB) {
    const int b = blockIdx.x, t = threadIdx.x;
    if (b < HB) {
        for (int e = b * 256 + t; e < E; e += HB * 256)
            atomicAdd(&deg[idx[E + e]], 1);
    } else if (b < HB + LNB) {
        const int row = (b - HB) * 4 + (t >> 6);
        if (row >= N) return;
        const int lane = t & 63;
        const size_t base = (size_t)row * 128 + lane * 2;
        float2 v = *(const float2*)&x[base];
        float s = v.x + v.y;
        #pragma unroll
        for (int o = 32; o; o >>= 1) s += __shfl_xor(s, o, 64);
        const float mu = s * 0.0078125f;
        const float d0 = v.x - mu, d1 = v.y - mu;
        float ss = d0 * d0 + d1 * d1;
        #pragma unroll
        for (int o = 32; o; o >>= 1) ss += __shfl_xor(ss, o, 64);
        const float rs = rsqrtf(ss * 0.0078125f + 1e-5f);
        float2 g = *(const float2*)&gamma[lane * 2];
        float2 bb = *(const float2*)&beta[lane * 2];
        float h0 = fmaxf(fmaf(d0 * rs, g.x, bb.x), 0.f);
        float h1 = fmaxf(fmaf(d1 * rs, g.y, bb.y), 0.f);
        hbuf[(size_t)row * 64 + lane] = (unsigned)f2bf(h0) | ((unsigned)f2bf(h1) << 16);
    } else {
        const int s = (b - HB - LNB) * 256 + t;     // 0..4095
        const int tc = s >> 9, c = (s >> 6) & 7, l = s & 63;
        const int n  = tc * 16 + (l & 15);
        const int k0 = c * 32 + ((l >> 4) & 3) * 8;
        const float* w = (k0 < 128) ? (Wl + (size_t)n * 128 + k0)
                                    : (Wr + (size_t)n * 128 + (k0 - 128));
        unsigned short tmp[8];
        #pragma unroll
        for (int j = 0; j < 8; j++) tmp[j] = f2bf(w[j]);
        *(short8*)&wsb[(size_t)s * 8] = *(short8*)tmp;
    }
}

// ---------------- K2: per-256-block exclusive scan of deg ---------------
__global__ __launch_bounds__(256) void scan1_kernel(
    const int* __restrict__ deg, int* __restrict__ excl,
    int* __restrict__ bsum, int N) {
    __shared__ int sd[256];
    const int t = threadIdx.x;
    const int i = blockIdx.x * 256 + t;
    const int v = (i < N) ? deg[i] : 0;
    sd[t] = v;
    __syncthreads();
    for (int off = 1; off < 256; off <<= 1) {
        int u = (t >= off) ? sd[t - off] : 0;
        __syncthreads();
        sd[t] += u;
        __syncthreads();
    }
    if (i <= N) excl[i] = sd[t] - v;
    if (t == 255) bsum[blockIdx.x] = sd[255];
}

// ---------------- K3: scan block sums (single block, NS1 <= 512) --------
__global__ __launch_bounds__(512) void scan2_kernel(
    int* __restrict__ bsum, int NS1) {
    __shared__ int sd[512];
    const int t = threadIdx.x;
    const int v = (t < NS1) ? bsum[t] : 0;
    sd[t] = v;
    __syncthreads();
    for (int off = 1; off < 512; off <<= 1) {
        int u = (t >= off) ? sd[t - off] : 0;
        __syncthreads();
        sd[t] += u;
        __syncthreads();
    }
    if (t < NS1) bsum[t] = sd[t] - v;    // exclusive block offsets, in-place
}

// ---------------- K4: combine -> nodestart[N+1], cur[N] -----------------
__global__ __launch_bounds__(256) void scan3_kernel(
    const int* __restrict__ excl, const int* __restrict__ bsum,
    int* __restrict__ nodestart, int* __restrict__ cur, int N) {
    const int i = blockIdx.x * 256 + threadIdx.x;
    if (i <= N) {
        const int v = excl[i] + bsum[blockIdx.x];
        nodestart[i] = v;
        if (i < N) cur[i] = v;
    }
}

// ---------------- K5: place src into fully dst-sorted sbuf --------------
__global__ __launch_bounds__(256) void place_kernel(
    const int* __restrict__ idx, int* __restrict__ cur,
    int* __restrict__ sbuf, int E) {
    const int stride = gridDim.x * 256;
    for (int e = blockIdx.x * 256 + threadIdx.x; e < E; e += stride) {
        const int src = idx[e];
        const int dst = idx[E + e];
        const int pos = atomicAdd(&cur[dst], 1);
        sbuf[pos] = src;
    }
}

// ---------------- K6: wave-per-node mean aggregation -> bf16 mbuf -------
// No LDS, no syncs: pure TLP/MLP. Lane l owns channel pair (2l, 2l+1).
__global__ __launch_bounds__(256) void gather_kernel(
    const unsigned* __restrict__ hbuf, const int* __restrict__ sbuf,
    const int* __restrict__ nodestart, unsigned* __restrict__ mbuf, int N) {
    const int node = blockIdx.x * 4 + (threadIdx.x >> 6);
    if (node >= N) return;
    const int l = threadIdx.x & 63;
    const int sp = nodestart[node], ep = nodestart[node + 1];
    float a0 = 0.f, a1 = 0.f;
    for (int j = sp; j < ep; j += 64) {
        const int nloc = min(ep - j, 64);
        const int sv = (l < nloc) ? sbuf[j + l] : 0;   // coalesced seg load
        int k = 0;
        for (; k + 8 <= nloc; k += 8) {
            unsigned p[8];
            #pragma unroll
            for (int u = 0; u < 8; u++) {
                const int sidx = __shfl(sv, k + u, 64);
                p[u] = hbuf[(size_t)sidx * 64 + l];
            }
            #pragma unroll
            for (int u = 0; u < 8; u++) {
                a0 += bf2f((unsigned short)(p[u] & 0xffffu));
                a1 += bf2f((unsigned short)(p[u] >> 16));
            }
        }
        for (; k < nloc; k++) {
            const int sidx = __shfl(sv, k, 64);
            const unsigned p = hbuf[(size_t)sidx * 64 + l];
            a0 += bf2f((unsigned short)(p & 0xffffu));
            a1 += bf2f((unsigned short)(p >> 16));
        }
    }
    const int dv = ep - sp;
    const float inv = (dv > 0) ? 1.f / (float)dv : 0.f;  // same quantization point as old P2
    mbuf[(size_t)node * 64 + l] = (unsigned)f2bf(a0 * inv) | ((unsigned)f2bf(a1 * inv) << 16);
}

// ---------------- K7: dense MFMA  out = [mean||h] @ Wcat^T + bl + x -----
// Block = 64 rows, wave w = 16 rows x all 128 cols. No LDS, no syncs.
__global__ __launch_bounds__(256) void mm_kernel(
    float* __restrict__ out, const unsigned* __restrict__ hbuf,
    const unsigned* __restrict__ mbuf, const float* __restrict__ x,
    const unsigned short* __restrict__ wsb, const float* __restrict__ bl, int N) {
    const int t = threadIdx.x, w = t >> 6, l = t & 63;
    const int rowbase = blockIdx.x * 64 + w * 16;
    if (rowbase >= N) return;
    const int r = l & 15, q = l >> 4;
    const int arow = min(rowbase + r, N - 1);
    const unsigned short* mp = (const unsigned short*)mbuf + (size_t)arow * 128 + q * 8;
    const unsigned short* hp = (const unsigned short*)hbuf + (size_t)arow * 128 + q * 8;
    short8 af[8];                          // A-frag: row=lane&15, k=(lane>>4)*8+j
    #pragma unroll
    for (int c = 0; c < 4; c++) af[c]     = *(const short8*)(mp + c * 32);
    #pragma unroll
    for (int c = 0; c < 4; c++) af[4 + c] = *(const short8*)(hp + c * 32);
    #pragma unroll
    for (int cc = 0; cc < 8; cc++) {       // 8 col-tiles of 16
        float4v acc = {0.f, 0.f, 0.f, 0.f};
        const short8* bw = (const short8*)wsb + (size_t)cc * 512;
        #pragma unroll
        for (int c = 0; c < 8; c++)
            acc = __builtin_amdgcn_mfma_f32_16x16x32_bf16(af[c], bw[c * 64 + l], acc, 0, 0, 0);
        const int col = cc * 16 + r;
        const float blv = bl[col];
        #pragma unroll
        for (int rr = 0; rr < 4; rr++) {   // C/D: col=lane&15, row=(lane>>4)*4+rr
            const int row = rowbase + q * 4 + rr;
            if (row < N)
                out[(size_t)row * 128 + col] = acc[rr] + blv + x[(size_t)row * 128 + col];
        }
    }
}

extern "C" void kernel_launch(void* const* d_in, const int* in_sizes, int n_in,
                              void* d_out, int out_size, void* d_ws, size_t ws_size,
                              hipStream_t stream) {
    const float* x     = (const float*)d_in[0];
    const int*   ei    = (const int*)d_in[1];
    const float* gamma = (const float*)d_in[2];
    const float* beta  = (const float*)d_in[3];
    const float* Wl    = (const float*)d_in[4];
    const float* bl    = (const float*)d_in[5];
    const float* Wr    = (const float*)d_in[6];
    float* out = (float*)d_out;

    const int C = 128;
    const int N = in_sizes[0] / C;          // 100000
    const int E = in_sizes[1] / 2;          // 1600000

    char* ws = (char*)d_ws;
    size_t off = 0;
    unsigned* hbuf = (unsigned*)(ws + off); off += (size_t)N * 256;   // 25.6 MB bf16 h
    unsigned* mbuf = (unsigned*)(ws + off); off += (size_t)N * 256;   // 25.6 MB bf16 mean
    int* sbuf      = (int*)(ws + off);      off += (size_t)E * 4;     // 6.4 MB sorted src
    const size_t NP4 = ((size_t)(N + 64) * 4 + 255) & ~(size_t)255;   // keep 16B align
    int* deg       = (int*)(ws + off);      off += NP4;
    int* excl      = (int*)(ws + off);      off += NP4;
    int* nodestart = (int*)(ws + off);      off += NP4;
    int* cur       = (int*)(ws + off);      off += NP4;
    int* bsum      = (int*)(ws + off);      off += 4096;
    unsigned short* wsb = (unsigned short*)(ws + off);                // 64 KB packed W

    const int LNB = (N + 3) / 4;            // 25000 LN blocks (4 rows each)
    const int NS1 = (N + 256) / 256;        // scan blocks covering N+1 entries (391)

    hipMemsetAsync(deg, 0, (size_t)N * 4, stream);
    fused_pre_kernel<<<HB + LNB + 16, 256, 0, stream>>>(
        x, gamma, beta, hbuf, ei, deg, Wl, Wr, wsb, N, E, LNB);
    scan1_kernel<<<NS1, 256, 0, stream>>>(deg, excl, bsum, N);
    scan2_kernel<<<1, 512, 0, stream>>>(bsum, NS1);
    scan3_kernel<<<NS1, 256, 0, stream>>>(excl, bsum, nodestart, cur, N);
    place_kernel<<<1024, 256, 0, stream>>>(ei, cur, sbuf, E);
    gather_kernel<<<(N + 3) / 4, 256, 0, stream>>>(hbuf, sbuf, nodestart, mbuf, N);
    mm_kernel<<<(N + 63) / 64, 256, 0, stream>>>(out, hbuf, mbuf, x, wsb, bl, N);
}